// Round 9
// baseline (437.882 us; speedup 1.0000x reference)
//
#include <hip/hip_runtime.h>

typedef unsigned short ushort_t;
typedef __bf16 bf16x8 __attribute__((ext_vector_type(8)));
typedef float f32x4 __attribute__((ext_vector_type(4)));

// sizes (fixed by the problem)
#define NB 8
#define BB 2
#define TT 2048
#define DD 2048
#define FF 8192
#define MM (BB * TT)          // 4096 rows
#define BTD ((size_t)BB * TT * DD)   // 8388608

__device__ __forceinline__ unsigned short f2bf(float f) {
  unsigned int u = __float_as_uint(f);
  u += 0x7FFFu + ((u >> 16) & 1u);
  return (unsigned short)(u >> 16);
}

__device__ __forceinline__ float gelu_tanh(float x) {
  float u = 0.7978845608028654f * (x + 0.044715f * x * x * x);
  float e = __expf(2.0f * u);
  float th = 1.0f - 2.0f / (e + 1.0f);   // robust tanh(u), e=inf -> 1
  return 0.5f * x * (1.0f + th);
}

template <int N>
__device__ __forceinline__ void wait_vmcnt() {
  if constexpr (N == 0) asm volatile("s_waitcnt vmcnt(0)" ::: "memory");
  else if constexpr (N == 6) asm volatile("s_waitcnt vmcnt(6)" ::: "memory");
  else if constexpr (N == 8) asm volatile("s_waitcnt vmcnt(8)" ::: "memory");
}

#define ASYNC_COPY16(gp, lp)                                                   \
  __builtin_amdgcn_global_load_lds(                                            \
      (__attribute__((address_space(1))) void*)(gp),                           \
      (__attribute__((address_space(3))) void*)(lp), 16, 0, 0)

// ---------------------------------------------------------------------------
// fp32 (R x C) -> bf16 transposed (C x R)
__global__ __launch_bounds__(256) void transpose_conv(
    const float* __restrict__ in, ushort_t* __restrict__ out, int R, int C) {
  __shared__ float tile[32][33];
  const int tx = threadIdx.x & 31, ty = threadIdx.x >> 5;
  const int r0 = blockIdx.y * 32, c0 = blockIdx.x * 32;
#pragma unroll
  for (int i = 0; i < 32; i += 8)
    tile[ty + i][tx] = in[(size_t)(r0 + ty + i) * C + (c0 + tx)];
  __syncthreads();
#pragma unroll
  for (int i = 0; i < 32; i += 8)
    out[(size_t)(c0 + ty + i) * R + (r0 + tx)] = f2bf(tile[tx][ty + i]);
}

// ---------------------------------------------------------------------------
// Fused block-attention: ONE PASS over V (V rows held in registers).
__global__ __launch_bounds__(256) void attn_fuse(
    const float* __restrict__ blocks, const float* __restrict__ partial,
    const float* __restrict__ proj_w, const float* __restrict__ norm_scale,
    float* __restrict__ h_out, ushort_t* __restrict__ h_bf) {
  const int t = threadIdx.x;
  const int bt = blockIdx.x;
  const size_t rowoff = (size_t)bt * DD;
  const int d0 = t * 4;

  float w[8];
  {
    float4 ns = *(const float4*)(norm_scale + d0);
    float4 pw = *(const float4*)(proj_w + d0);
    w[0] = ns.x * pw.x; w[1] = ns.y * pw.y; w[2] = ns.z * pw.z; w[3] = ns.w * pw.w;
    ns = *(const float4*)(norm_scale + 1024 + d0);
    pw = *(const float4*)(proj_w + 1024 + d0);
    w[4] = ns.x * pw.x; w[5] = ns.y * pw.y; w[6] = ns.z * pw.z; w[7] = ns.w * pw.w;
  }

  float vv[9][8];
  float ss[9], dt[9];
#pragma unroll
  for (int n = 0; n < 9; ++n) {
    const float* rp = (n < 8) ? (blocks + (size_t)n * BTD + rowoff)
                              : (partial + rowoff);
    float4 v0 = *(const float4*)(rp + d0);
    float4 v1 = *(const float4*)(rp + 1024 + d0);
    vv[n][0] = v0.x; vv[n][1] = v0.y; vv[n][2] = v0.z; vv[n][3] = v0.w;
    vv[n][4] = v1.x; vv[n][5] = v1.y; vv[n][6] = v1.z; vv[n][7] = v1.w;
    float a = 0.f, c = 0.f;
#pragma unroll
    for (int j = 0; j < 8; ++j) {
      a += vv[n][j] * vv[n][j];
      c += vv[n][j] * w[j];
    }
    ss[n] = a; dt[n] = c;
  }

  __shared__ float red[2][9][4];
  const int lane = t & 63, wv = t >> 6;
#pragma unroll
  for (int n = 0; n < 9; ++n) {
    float a = ss[n], c = dt[n];
#pragma unroll
    for (int off = 32; off > 0; off >>= 1) {
      a += __shfl_down(a, off, 64);
      c += __shfl_down(c, off, 64);
    }
    if (lane == 0) { red[0][n][wv] = a; red[1][n][wv] = c; }
  }
  __syncthreads();
  __shared__ float logit_s[9];
  if (t < 9) {
    float a = red[0][t][0] + red[0][t][1] + red[0][t][2] + red[0][t][3];
    float c = red[1][t][0] + red[1][t][1] + red[1][t][2] + red[1][t][3];
    logit_s[t] = c * rsqrtf(a * (1.0f / (float)DD) + 1e-8f);
  }
  __syncthreads();

  float lg[9], mx = -1e30f;
#pragma unroll
  for (int n = 0; n < 9; ++n) { lg[n] = logit_s[n]; mx = fmaxf(mx, lg[n]); }
  float den = 0.0f;
#pragma unroll
  for (int n = 0; n < 9; ++n) { lg[n] = __expf(lg[n] - mx); den += lg[n]; }
  const float inv = 1.0f / den;

  float h[8] = {0, 0, 0, 0, 0, 0, 0, 0};
#pragma unroll
  for (int n = 0; n < 9; ++n) {
    const float a = lg[n] * inv;
#pragma unroll
    for (int j = 0; j < 8; ++j) h[j] += a * vv[n][j];
  }

  float4 o0 = {h[0], h[1], h[2], h[3]}, o1 = {h[4], h[5], h[6], h[7]};
  *(float4*)(h_out + rowoff + d0) = o0;
  *(float4*)(h_out + rowoff + 1024 + d0) = o1;
  uint2 p0, p1;
  p0.x = (unsigned)f2bf(h[0]) | ((unsigned)f2bf(h[1]) << 16);
  p0.y = (unsigned)f2bf(h[2]) | ((unsigned)f2bf(h[3]) << 16);
  p1.x = (unsigned)f2bf(h[4]) | ((unsigned)f2bf(h[5]) << 16);
  p1.y = (unsigned)f2bf(h[6]) | ((unsigned)f2bf(h[7]) << 16);
  *(uint2*)(h_bf + rowoff + d0) = p0;
  *(uint2*)(h_bf + rowoff + 1024 + d0) = p1;
}

// ---------------------------------------------------------------------------
// Fully register-pipelined quad-ring bf16 GEMM, 4 waves @ 1 wave/SIMD.
// BM=256, BK=32 sub-tiles, ring of 4 LDS buffers, ONE barrier per sub-tile.
// 4 waves (2M x 2N), wave tile 128 x (BN/2): MFR=8, NFR=BN/32.
// Why this geometry (from the R2-R8 33-39% plateau arithmetic):
//  - 4 waves => LDS read amplification 2xA + 2xB = 64KB/subtile (BN=256)
//    vs 96KB with 8 waves: LDS time 1130 cyc < MFMA issue 1242 cyc.
//  - 1 wave/SIMD => 512-reg unified budget/wave: acc 256 AGPR + DOUBLE
//    fragment set 2x16 b128 = 128 VGPR fits ((512,2)'s 256 cap could not
//    -> R4 spill). Frags for sub-tile t+1 are ds_read DURING interval t
//    while MFMA(t) runs on regs read in t-1: MFMA never waits on
//    same-interval LDS (compiler emits counted lgkm), so ds_read drains
//    under the MFMA stream - single-wave ILP, no cross-wave convoy.
// Interval t: stage(t+3)->buf[t+3 &3] (last read 2 barriers ago, race-free);
// read frags(t+1) from buf(t+1) (landed: prologue/steady vmcnt(LT) leaves
// only stage(t+3) in flight); 64|32 MFMA on frags(t); vmcnt(LT|0); barrier.
// LDS rowpair-packed XOR layout (0 bank conflicts, verified R7/R8).
// EPI=0: C = gelu(A@B) -> bf16.  EPI=1: C = A@B + addend -> fp32.
template <int BN, int SBY, int SBX, int MCX, int EPI>
__global__ __launch_bounds__(256, 1) void gemmP(
    const ushort_t* __restrict__ A, const ushort_t* __restrict__ BT,
    const int K, const int N, ushort_t* __restrict__ Cb,
    const float* __restrict__ addend, float* __restrict__ Cf) {
  constexpr int MFR = 8;               // m-frags per wave (128 rows)
  constexpr int NFR = BN / 32;         // n-frags per wave (8 | 4)
  constexpr int AS = 16384;            // A sub-tile bytes (256 x 32 x 2B)
  constexpr int BS = BN * 64;          // B sub-tile bytes
  constexpr int RS = AS + BS;          // ring stride
  constexpr int LA = 4;                // A stage batches (4096 B each)
  constexpr int LBN = BS / 4096;       // B stage batches (4 | 2)
  constexpr int LT = LA + LBN;         // loads/thread/sub-tile (8 | 6)

  __shared__ __align__(16) char lds[4 * RS];

  const int t = threadIdx.x;
  const int lane = t & 63, wv = t >> 6;
  const int fr = lane & 15, kslot = lane >> 4;
  const int WRow = (wv >> 1) * 128;
  const int WCol = (wv & 1) * (BN / 2);

  // 2D XCD supertile
  const int wg = blockIdx.x;
  const int xcd = wg & 7, local = wg >> 3;
  const int by = (xcd / MCX) * SBY + local / SBX;
  const int bx = (xcd % MCX) * SBX + local % SBX;
  const int row0 = by * 256, col0 = bx * BN;

  // staging sources: thread covers LDS bytes o = j*4096 + t*16 (linear dest);
  // global element = inverse of the rowpair+XOR layout.
  const ushort_t* ga[LA];
  const ushort_t* gb[LBN];
#pragma unroll
  for (int j = 0; j < LA; ++j) {
    const int o = j * 4096 + t * 16;
    const int rp = o >> 7;
    const int iX = (o & 127) ^ ((rp & 7) << 4);
    ga[j] = A + (size_t)(row0 + rp * 2 + (iX >> 6)) * K + ((iX & 63) >> 1);
  }
#pragma unroll
  for (int j = 0; j < LBN; ++j) {
    const int o = j * 4096 + t * 16;
    const int rp = o >> 7;
    const int iX = (o & 127) ^ ((rp & 7) << 4);
    gb[j] = BT + (size_t)(col0 + rp * 2 + (iX >> 6)) * K + ((iX & 63) >> 1);
  }

#define STAGE(QQ, KT)                                                          \
  {                                                                            \
    _Pragma("unroll") for (int j = 0; j < LA; ++j)                             \
      ASYNC_COPY16(ga[j] + (size_t)(KT) * 32,                                  \
                   lds + (QQ)*RS + j * 4096 + t * 16);                         \
    _Pragma("unroll") for (int j = 0; j < LBN; ++j)                            \
      ASYNC_COPY16(gb[j] + (size_t)(KT) * 32,                                  \
                   lds + (QQ)*RS + AS + j * 4096 + t * 16);                    \
  }

  // fragment read offsets: row r = W{Row,Col}+m*16+fr, k = kslot*8..+8:
  // byte = (r>>1)*128 + ((((r&1)<<6)|(kslot<<4)) ^ (((r>>1)&7)<<4));
  // rp&7 is m-independent (m*16 rows = 8 rowpairs, multiple of 8).
  const int arp0 = (WRow + fr) >> 1;
  const int aoff =
      arp0 * 128 + (((((fr & 1) << 6) | (kslot << 4))) ^ ((arp0 & 7) << 4));
  const int brp0 = (WCol + fr) >> 1;
  const int boff = AS + brp0 * 128 +
                   (((((fr & 1) << 6) | (kslot << 4))) ^ ((brp0 & 7) << 4));

  // double fragment set: frags(t) consumed while frags(t+1) read
  bf16x8 a0[MFR], b0[NFR], a1[MFR], b1[NFR];

#define READF(AX, BX, Lb)                                                      \
  {                                                                            \
    _Pragma("unroll") for (int m = 0; m < MFR; ++m)                            \
      AX[m] = *(const bf16x8*)((Lb) + aoff + m * 1024);                        \
    _Pragma("unroll") for (int n = 0; n < NFR; ++n)                            \
      BX[n] = *(const bf16x8*)((Lb) + boff + n * 1024);                        \
  }

  f32x4 acc[MFR][NFR];
#pragma unroll
  for (int m = 0; m < MFR; ++m)
#pragma unroll
    for (int n = 0; n < NFR; ++n) {
      f32x4 z = {0.f, 0.f, 0.f, 0.f};
      acc[m][n] = z;
    }

#define MFMA_(a, b, c) __builtin_amdgcn_mfma_f32_16x16x32_bf16(a, b, c, 0, 0, 0)

#define INTERVAL(QQ, KT, AC, BC, AN, BNX)                                      \
  {                                                                            \
    if ((KT) + 3 < NT) STAGE(((QQ) + 3) & 3, (KT) + 3);                        \
    if ((KT) + 1 < NT) {                                                       \
      const char* Ln = lds + (((QQ) + 1) & 3) * RS;                            \
      READF(AN, BNX, Ln);                                                      \
    }                                                                          \
    __builtin_amdgcn_s_setprio(1);                                             \
    _Pragma("unroll") for (int m = 0; m < MFR; ++m)                            \
      _Pragma("unroll") for (int n = 0; n < NFR; ++n)                          \
        acc[m][n] = MFMA_(AC[m], BC[n], acc[m][n]);                            \
    __builtin_amdgcn_s_setprio(0);                                             \
    if ((KT) + 3 < NT) wait_vmcnt<LT>(); else wait_vmcnt<0>();                 \
    __builtin_amdgcn_s_barrier();                                              \
  }

  const int NT = K >> 5;  // sub-tiles of K=32 (64 or 256; multiple of 4)

  // prologue: stage 0,1,2; wait tiles 0,1 landed (leave 2 in flight);
  // pre-read frags(0).
  STAGE(0, 0);
  STAGE(1, 1);
  STAGE(2, 2);
  wait_vmcnt<LT>();
  __builtin_amdgcn_s_barrier();
  READF(a0, b0, (const char*)lds);

  for (int t0 = 0; t0 < NT; t0 += 4) {
    INTERVAL(0, t0 + 0, a0, b0, a1, b1);
    INTERVAL(1, t0 + 1, a1, b1, a0, b0);
    INTERVAL(2, t0 + 2, a0, b0, a1, b1);
    INTERVAL(3, t0 + 3, a1, b1, a0, b0);
  }

  const int r4 = kslot * 4;
#pragma unroll
  for (int m = 0; m < MFR; ++m) {
    const int grow = row0 + WRow + m * 16 + r4;
#pragma unroll
    for (int n = 0; n < NFR; ++n) {
      const int gcol = col0 + WCol + n * 16 + fr;
#pragma unroll
      for (int r = 0; r < 4; ++r) {
        const float v = acc[m][n][r];
        const size_t idx = (size_t)(grow + r) * N + gcol;
        if (EPI == 0) {
          Cb[idx] = f2bf(gelu_tanh(v));
        } else {
          Cf[idx] = v + addend[idx];
        }
      }
    }
  }
#undef INTERVAL
#undef MFMA_
#undef READF
#undef STAGE
}

// ---------------------------------------------------------------------------
extern "C" void kernel_launch(void* const* d_in, const int* in_sizes, int n_in,
                              void* d_out, int out_size, void* d_ws,
                              size_t ws_size, hipStream_t stream) {
  const float* blocks = (const float*)d_in[0];
  const float* partial = (const float*)d_in[1];
  const float* proj_w = (const float*)d_in[2];
  const float* norm_scale = (const float*)d_in[3];
  const float* w1 = (const float*)d_in[4];
  const float* w2 = (const float*)d_in[5];

  float* out = (float*)d_out;
  float* h_out = out;                 // [B,T,D] fp32
  float* new_partial = out + BTD;     // [B,T,D] fp32

  char* ws = (char*)d_ws;
  ushort_t* h_bf = (ushort_t*)ws;                                        // 16 MB
  ushort_t* w1T = (ushort_t*)(ws + (size_t)16777216);                    // 32 MB (F x D)
  ushort_t* w2T = (ushort_t*)(ws + (size_t)16777216 + 33554432);         // 32 MB (D x F)
  ushort_t* act = (ushort_t*)(ws + (size_t)16777216 + 2 * 33554432ull);  // 64 MB (M x F)

  // weight convert + transpose to (N x K) bf16
  transpose_conv<<<dim3(FF / 32, DD / 32), 256, 0, stream>>>(w1, w1T, DD, FF);
  transpose_conv<<<dim3(DD / 32, FF / 32), 256, 0, stream>>>(w2, w2T, FF, DD);

  // fused attention -> h (fp32 out) + h (bf16 for GEMM)
  attn_fuse<<<MM, 256, 0, stream>>>(blocks, partial, proj_w, norm_scale, h_out,
                                    h_bf);

  // FFN: act = gelu(h @ W1) ; new_partial = act @ W2 + partial
  // GEMM1: 256x256 tile, 4 waves (wave 128x128), grid 16x32=512 (2 passes),
  //        supertile 8x8 per XCD (macro 2x4).
  gemmP<256, 8, 8, 4, 0><<<512, 256, 0, stream>>>(
      h_bf, w1T, DD, FF, act, nullptr, nullptr);
  // GEMM2: 256x128 tile, 4 waves (wave 128x64), grid 16x16=256,
  //        supertile 4x8 per XCD (macro 4x2).
  gemmP<128, 4, 8, 2, 1><<<256, 256, 0, stream>>>(
      act, w2T, FF, DD, nullptr, partial, new_partial);
}

// Round 10
// 421.237 us; speedup vs baseline: 1.0395x; 1.0395x over previous
//
#include <hip/hip_runtime.h>

typedef unsigned short ushort_t;
typedef __bf16 bf16x8 __attribute__((ext_vector_type(8)));
typedef float f32x4 __attribute__((ext_vector_type(4)));

// sizes (fixed by the problem)
#define NB 8
#define BB 2
#define TT 2048
#define DD 2048
#define FF 8192
#define MM (BB * TT)          // 4096 rows
#define BTD ((size_t)BB * TT * DD)   // 8388608

__device__ __forceinline__ unsigned short f2bf(float f) {
  unsigned int u = __float_as_uint(f);
  u += 0x7FFFu + ((u >> 16) & 1u);
  return (unsigned short)(u >> 16);
}

__device__ __forceinline__ float gelu_tanh(float x) {
  float u = 0.7978845608028654f * (x + 0.044715f * x * x * x);
  float e = __expf(2.0f * u);
  float th = 1.0f - 2.0f / (e + 1.0f);   // robust tanh(u), e=inf -> 1
  return 0.5f * x * (1.0f + th);
}

template <int N>
__device__ __forceinline__ void wait_vmcnt() {
  if constexpr (N == 0) asm volatile("s_waitcnt vmcnt(0)" ::: "memory");
  else if constexpr (N == 2) asm volatile("s_waitcnt vmcnt(2)" ::: "memory");
  else if constexpr (N == 4) asm volatile("s_waitcnt vmcnt(4)" ::: "memory");
}

#define ASYNC_COPY16(gp, lp)                                                   \
  __builtin_amdgcn_global_load_lds(                                            \
      (__attribute__((address_space(1))) void*)(gp),                           \
      (__attribute__((address_space(3))) void*)(lp), 16, 0, 0)

// ---------------------------------------------------------------------------
// fp32 (R x C) -> bf16 transposed (C x R)
__global__ __launch_bounds__(256) void transpose_conv(
    const float* __restrict__ in, ushort_t* __restrict__ out, int R, int C) {
  __shared__ float tile[32][33];
  const int tx = threadIdx.x & 31, ty = threadIdx.x >> 5;
  const int r0 = blockIdx.y * 32, c0 = blockIdx.x * 32;
#pragma unroll
  for (int i = 0; i < 32; i += 8)
    tile[ty + i][tx] = in[(size_t)(r0 + ty + i) * C + (c0 + tx)];
  __syncthreads();
#pragma unroll
  for (int i = 0; i < 32; i += 8)
    out[(size_t)(c0 + ty + i) * R + (r0 + tx)] = f2bf(tile[tx][ty + i]);
}

// ---------------------------------------------------------------------------
// Fused block-attention: ONE PASS over V (V rows held in registers).
__global__ __launch_bounds__(256) void attn_fuse(
    const float* __restrict__ blocks, const float* __restrict__ partial,
    const float* __restrict__ proj_w, const float* __restrict__ norm_scale,
    float* __restrict__ h_out, ushort_t* __restrict__ h_bf) {
  const int t = threadIdx.x;
  const int bt = blockIdx.x;
  const size_t rowoff = (size_t)bt * DD;
  const int d0 = t * 4;

  float w[8];
  {
    float4 ns = *(const float4*)(norm_scale + d0);
    float4 pw = *(const float4*)(proj_w + d0);
    w[0] = ns.x * pw.x; w[1] = ns.y * pw.y; w[2] = ns.z * pw.z; w[3] = ns.w * pw.w;
    ns = *(const float4*)(norm_scale + 1024 + d0);
    pw = *(const float4*)(proj_w + 1024 + d0);
    w[4] = ns.x * pw.x; w[5] = ns.y * pw.y; w[6] = ns.z * pw.z; w[7] = ns.w * pw.w;
  }

  float vv[9][8];
  float ss[9], dt[9];
#pragma unroll
  for (int n = 0; n < 9; ++n) {
    const float* rp = (n < 8) ? (blocks + (size_t)n * BTD + rowoff)
                              : (partial + rowoff);
    float4 v0 = *(const float4*)(rp + d0);
    float4 v1 = *(const float4*)(rp + 1024 + d0);
    vv[n][0] = v0.x; vv[n][1] = v0.y; vv[n][2] = v0.z; vv[n][3] = v0.w;
    vv[n][4] = v1.x; vv[n][5] = v1.y; vv[n][6] = v1.z; vv[n][7] = v1.w;
    float a = 0.f, c = 0.f;
#pragma unroll
    for (int j = 0; j < 8; ++j) {
      a += vv[n][j] * vv[n][j];
      c += vv[n][j] * w[j];
    }
    ss[n] = a; dt[n] = c;
  }

  __shared__ float red[2][9][4];
  const int lane = t & 63, wv = t >> 6;
#pragma unroll
  for (int n = 0; n < 9; ++n) {
    float a = ss[n], c = dt[n];
#pragma unroll
    for (int off = 32; off > 0; off >>= 1) {
      a += __shfl_down(a, off, 64);
      c += __shfl_down(c, off, 64);
    }
    if (lane == 0) { red[0][n][wv] = a; red[1][n][wv] = c; }
  }
  __syncthreads();
  __shared__ float logit_s[9];
  if (t < 9) {
    float a = red[0][t][0] + red[0][t][1] + red[0][t][2] + red[0][t][3];
    float c = red[1][t][0] + red[1][t][1] + red[1][t][2] + red[1][t][3];
    logit_s[t] = c * rsqrtf(a * (1.0f / (float)DD) + 1e-8f);
  }
  __syncthreads();

  float lg[9], mx = -1e30f;
#pragma unroll
  for (int n = 0; n < 9; ++n) { lg[n] = logit_s[n]; mx = fmaxf(mx, lg[n]); }
  float den = 0.0f;
#pragma unroll
  for (int n = 0; n < 9; ++n) { lg[n] = __expf(lg[n] - mx); den += lg[n]; }
  const float inv = 1.0f / den;

  float h[8] = {0, 0, 0, 0, 0, 0, 0, 0};
#pragma unroll
  for (int n = 0; n < 9; ++n) {
    const float a = lg[n] * inv;
#pragma unroll
    for (int j = 0; j < 8; ++j) h[j] += a * vv[n][j];
  }

  float4 o0 = {h[0], h[1], h[2], h[3]}, o1 = {h[4], h[5], h[6], h[7]};
  *(float4*)(h_out + rowoff + d0) = o0;
  *(float4*)(h_out + rowoff + 1024 + d0) = o1;
  uint2 p0, p1;
  p0.x = (unsigned)f2bf(h[0]) | ((unsigned)f2bf(h[1]) << 16);
  p0.y = (unsigned)f2bf(h[2]) | ((unsigned)f2bf(h[3]) << 16);
  p1.x = (unsigned)f2bf(h[4]) | ((unsigned)f2bf(h[5]) << 16);
  p1.y = (unsigned)f2bf(h[6]) | ((unsigned)f2bf(h[7]) << 16);
  *(uint2*)(h_bf + rowoff + d0) = p0;
  *(uint2*)(h_bf + rowoff + 1024 + d0) = p1;
}

// ---------------------------------------------------------------------------
// m201-template 8-phase bf16 GEMM (attempt #4, exact-fidelity).
// BM=256, BK=64, 8 waves (2M x 4N), per-wave 128 x (BN/4).  LDS: 2 tile
// buffers X,Y (A 32KB + B BN/4 KB each).  Per ITERATION (2 K-tiles a in X,
// a+1 in Y), 8 phases; each phase = { ds_reads ; 2 stage-loads ; s_barrier ;
// setprio(1) ; MFMA quadrant ; setprio(0) ; [vmcnt @P4/P8] ; s_barrier }.
// Quadrants Gray-coded (m0n0, m0n1, m1n1, m1n0): reads/K-tile {12,4,8,0};
// B-n0 frags held in regs from P1 to P4.  NO sched_barrier (m141: pinning
// costs 40%), NO inline lgkm (compiler's per-dep counted lgkm lets early
// waves MFMA while late waves' reads drain - the template's overlap).
// Stage ledger (2 loads/phase, half-tile granularity; free/land verified):
//   P1: Y.A0(a+1)  P2: Y.A1(a+1)  P3: X.B0(a+2)  P4: X.B1(a+2)
//   P5: X.A0(a+2)  P6: X.A1(a+2)  P7: Y.B0(a+3)  P8: Y.B1(a+3)
// vmcnt(4) [BN=128: vmcnt(2)] at end-P4 (covers Y.A read at P5) and end-P8
// (covers X read at next P1); vmcnt(0) at tail iteration.
// XOR swizzle byte ^= ((row&7)<<4) via pre-swizzled global source (0 bank
// conflicts, verified R2-R9).
// EPI=0: C = gelu(A@B) -> bf16.  EPI=1: C = A@B + addend -> fp32.
template <int BN, int EPI, int SBY, int SBX, int MCX>
__global__ __launch_bounds__(512, 2) void gemm8(
    const ushort_t* __restrict__ A, const ushort_t* __restrict__ BT,
    const int K, const int N, ushort_t* __restrict__ Cb,
    const float* __restrict__ addend, float* __restrict__ Cf) {
  constexpr int WCN = BN / 4;       // wave col span (64 | 32)
  constexpr int NFR = WCN / 16;     // n-frags per wave (4 | 2)
  constexpr int NH = NFR / 2;       // n-frags per quadrant (2 | 1)
  constexpr int NCB = BN / 64;      // B chunks (4 | 2)
  constexpr int AUS = 256 * 64;     // A region in ushorts (32 KB)
  constexpr int VMC = (BN == 256) ? 4 : 2;

  __shared__ __align__(16) ushort_t lds0[(256 + BN) * 64];
  __shared__ __align__(16) ushort_t lds1[(256 + BN) * 64];

  const int t = threadIdx.x;
  const int lane = t & 63, wv = t >> 6;
  const int wr = wv >> 2, wc = wv & 3;
  const int fr = lane & 15;

  // 2D XCD supertile (FETCH 270->150MB, verified R7/R8)
  const int wg = blockIdx.x;
  const int xcd = wg & 7, local = wg >> 3;
  const int by = (xcd / MCX) * SBY + local / SBX;
  const int bx = (xcd % MCX) * SBX + local % SBX;
  const int row0 = by * 256, col0 = bx * BN;

  // staging: thread t covers 16B at (row = chunk*64 + t/8, colbyte pre-swz)
  const int sr = t >> 3;
  const int scolb = ((t & 7) * 16) ^ ((sr & 7) << 4);  // inverse-swizzled src
  const ushort_t* gA = A + (size_t)(row0 + sr) * K + (scolb >> 1);
  const ushort_t* gB = BT + (size_t)(col0 + sr) * K + (scolb >> 1);

#define ST_A(W, c, KT)                                                         \
  ASYNC_COPY16(gA + (size_t)((c)*64) * K + (KT)*64, &W[(c)*4096 + wv * 512])
#define ST_B(W, c, KT)                                                         \
  ASYNC_COPY16(gB + (size_t)((c)*64) * K + (KT)*64,                            \
               &W[AUS + (c)*4096 + wv * 512])

  // frag read offsets: row*128 + ((ks*64 + (lane>>4)*16) ^ ((row&7)<<4));
  // row&7 == fr&7 for every frag row, so the XOR term is lane-constant.
  const int s_lane = (fr & 7) << 4;
  const int offk0 = ((lane >> 4) * 16) ^ s_lane;
  const int offk1 = (64 + (lane >> 4) * 16) ^ s_lane;
  const int aoffA = (wr * 128 + fr) * 128;  // + m*2048 bytes
  int boffB[NFR];
#pragma unroll
  for (int n = 0; n < NFR; ++n)
    boffB[n] = AUS * 2 + (wc * WCN + n * 16 + fr) * 128;

  // fragment regs: A half (8 b128) + B quadrant sets (held: bn0 P1->P4)
  bf16x8 af[4][2], bn0[NH][2], bn1[NH][2];

#define READ_A(Lb, MO)                                                         \
  _Pragma("unroll") for (int m = 0; m < 4; ++m) {                              \
    af[m][0] =                                                                 \
        *(const bf16x8*)((const char*)(Lb) + aoffA + (MO + m) * 2048 + offk0); \
    af[m][1] =                                                                 \
        *(const bf16x8*)((const char*)(Lb) + aoffA + (MO + m) * 2048 + offk1); \
  }
#define READ_B(Lb, DST, NO)                                                    \
  _Pragma("unroll") for (int n = 0; n < NH; ++n) {                             \
    DST[n][0] = *(const bf16x8*)((const char*)(Lb) + boffB[NO + n] + offk0);   \
    DST[n][1] = *(const bf16x8*)((const char*)(Lb) + boffB[NO + n] + offk1);   \
  }

  f32x4 acc[8][NFR];
#pragma unroll
  for (int m = 0; m < 8; ++m)
#pragma unroll
    for (int n = 0; n < NFR; ++n) {
      f32x4 z = {0.f, 0.f, 0.f, 0.f};
      acc[m][n] = z;
    }

#define MFMA_(a, b, c) __builtin_amdgcn_mfma_f32_16x16x32_bf16(a, b, c, 0, 0, 0)
#define QUAD(BF, MO, NO)                                                       \
  _Pragma("unroll") for (int ks = 0; ks < 2; ++ks)                             \
    _Pragma("unroll") for (int m = 0; m < 4; ++m)                              \
      _Pragma("unroll") for (int n = 0; n < NH; ++n)                           \
        acc[MO + m][NO + n] =                                                  \
            MFMA_(af[m][ks], BF[n][ks], acc[MO + m][NO + n]);

#define BAR __builtin_amdgcn_s_barrier()
#define PRIO1 __builtin_amdgcn_s_setprio(1)
#define PRIO0 __builtin_amdgcn_s_setprio(0)

#define ITER(X, Y, a)                                                          \
  {                                                                            \
    const bool s2 = (a) + 2 < NT, s3 = (a) + 3 < NT;                           \
    /* P1: X reads (B-n0 + A-m0); stage Y.A0(a+1); MFMA (m0,n0) */             \
    READ_B(X, bn0, 0);                                                         \
    READ_A(X, 0);                                                              \
    ST_A(Y, 0, (a) + 1); ST_A(Y, 1, (a) + 1);                                  \
    BAR; PRIO1; QUAD(bn0, 0, 0); PRIO0; BAR;                                   \
    /* P2: X read B-n1; stage Y.A1(a+1); MFMA (m0,n1) */                       \
    READ_B(X, bn1, NH);                                                        \
    ST_A(Y, 2, (a) + 1); ST_A(Y, 3, (a) + 1);                                  \
    BAR; PRIO1; QUAD(bn1, 0, NH); PRIO0; BAR;                                  \
    /* P3: X read A-m1; stage X.B0(a+2); MFMA (m1,n1) */                       \
    READ_A(X, 4);                                                              \
    if (s2) { ST_B(X, 0, (a) + 2); ST_B(X, 1, (a) + 2); }                      \
    BAR; PRIO1; QUAD(bn1, 4, NH); PRIO0; BAR;                                  \
    /* P4: stage X.B1(a+2); MFMA (m1,n0) on held bn0; vmcnt */                 \
    if (s2 && NCB == 4) { ST_B(X, 2, (a) + 2); ST_B(X, 3, (a) + 2); }          \
    BAR; PRIO1; QUAD(bn0, 4, 0); PRIO0;                                        \
    if (s2) wait_vmcnt<VMC>(); else wait_vmcnt<0>();                           \
    BAR;                                                                       \
    /* P5: Y reads (B-n0 + A-m0); stage X.A0(a+2); MFMA (m0,n0) */             \
    READ_B(Y, bn0, 0);                                                         \
    READ_A(Y, 0);                                                              \
    if (s2) { ST_A(X, 0, (a) + 2); ST_A(X, 1, (a) + 2); }                      \
    BAR; PRIO1; QUAD(bn0, 0, 0); PRIO0; BAR;                                   \
    /* P6: Y read B-n1; stage X.A1(a+2); MFMA (m0,n1) */                       \
    READ_B(Y, bn1, NH);                                                        \
    if (s2) { ST_A(X, 2, (a) + 2); ST_A(X, 3, (a) + 2); }                      \
    BAR; PRIO1; QUAD(bn1, 0, NH); PRIO0; BAR;                                  \
    /* P7: Y read A-m1; stage Y.B0(a+3); MFMA (m1,n1) */                       \
    READ_A(Y, 4);                                                              \
    if (s3) { ST_B(Y, 0, (a) + 3); ST_B(Y, 1, (a) + 3); }                      \
    BAR; PRIO1; QUAD(bn1, 4, NH); PRIO0; BAR;                                  \
    /* P8: stage Y.B1(a+3); MFMA (m1,n0) on held bn0; vmcnt */                 \
    if (s3 && NCB == 4) { ST_B(Y, 2, (a) + 3); ST_B(Y, 3, (a) + 3); }          \
    BAR; PRIO1; QUAD(bn0, 4, 0); PRIO0;                                        \
    if (s2) wait_vmcnt<VMC>(); else wait_vmcnt<0>();                           \
    BAR;                                                                       \
  }

  const int NT = K >> 6;  // K-tiles (even: 32 or 128)

  // prologue: X <- tile 0 (full), Y <- tile 1 (B only; A arrives P1-P2)
#pragma unroll
  for (int c = 0; c < NCB; ++c) ST_B(lds0, c, 0);
  ST_A(lds0, 0, 0); ST_A(lds0, 1, 0); ST_A(lds0, 2, 0); ST_A(lds0, 3, 0);
#pragma unroll
  for (int c = 0; c < NCB; ++c) ST_B(lds1, c, 1);
  wait_vmcnt<VMC>();  // tile 0 landed; Y.B in flight
  __builtin_amdgcn_s_barrier();

  for (int a = 0; a < NT; a += 2) ITER(lds0, lds1, a);

  const int r4 = (lane >> 4) * 4;
#pragma unroll
  for (int m = 0; m < 8; ++m) {
    const int grow = row0 + wr * 128 + m * 16 + r4;
#pragma unroll
    for (int n = 0; n < NFR; ++n) {
      const int gcol = col0 + wc * WCN + n * 16 + fr;
#pragma unroll
      for (int r = 0; r < 4; ++r) {
        const float v = acc[m][n][r];
        const size_t idx = (size_t)(grow + r) * N + gcol;
        if (EPI == 0) {
          Cb[idx] = f2bf(gelu_tanh(v));
        } else {
          Cf[idx] = v + addend[idx];
        }
      }
    }
  }
#undef ITER
#undef BAR
#undef PRIO1
#undef PRIO0
#undef QUAD
#undef MFMA_
#undef READ_A
#undef READ_B
#undef ST_A
#undef ST_B
}

// ---------------------------------------------------------------------------
extern "C" void kernel_launch(void* const* d_in, const int* in_sizes, int n_in,
                              void* d_out, int out_size, void* d_ws,
                              size_t ws_size, hipStream_t stream) {
  const float* blocks = (const float*)d_in[0];
  const float* partial = (const float*)d_in[1];
  const float* proj_w = (const float*)d_in[2];
  const float* norm_scale = (const float*)d_in[3];
  const float* w1 = (const float*)d_in[4];
  const float* w2 = (const float*)d_in[5];

  float* out = (float*)d_out;
  float* h_out = out;                 // [B,T,D] fp32
  float* new_partial = out + BTD;     // [B,T,D] fp32

  char* ws = (char*)d_ws;
  ushort_t* h_bf = (ushort_t*)ws;                                        // 16 MB
  ushort_t* w1T = (ushort_t*)(ws + (size_t)16777216);                    // 32 MB (F x D)
  ushort_t* w2T = (ushort_t*)(ws + (size_t)16777216 + 33554432);         // 32 MB (D x F)
  ushort_t* act = (ushort_t*)(ws + (size_t)16777216 + 2 * 33554432ull);  // 64 MB (M x F)

  // weight convert + transpose to (N x K) bf16
  transpose_conv<<<dim3(FF / 32, DD / 32), 256, 0, stream>>>(w1, w1T, DD, FF);
  transpose_conv<<<dim3(DD / 32, FF / 32), 256, 0, stream>>>(w2, w2T, FF, DD);

  // fused attention -> h (fp32 out) + h (bf16 for GEMM)
  attn_fuse<<<MM, 256, 0, stream>>>(blocks, partial, proj_w, norm_scale, h_out,
                                    h_bf);

  // FFN: act = gelu(h @ W1) ; new_partial = act @ W2 + partial
  // GEMM1: 256x256, grid 16x32=512; XCD supertile 8x8 (macro 2x4).
  gemm8<256, 0, 8, 8, 4><<<512, 512, 0, stream>>>(
      h_bf, w1T, DD, FF, act, nullptr, nullptr);
  // GEMM2: 256x128, grid 16x16=256; XCD supertile 4x8 (macro 4x2).
  gemm8<128, 1, 4, 8, 2><<<256, 512, 0, stream>>>(
      act, w2T, FF, DD, nullptr, partial, new_partial);
}

// Round 11
// 393.012 us; speedup vs baseline: 1.1142x; 1.0718x over previous
//
#include <hip/hip_runtime.h>

typedef unsigned short ushort_t;
typedef __bf16 bf16x8 __attribute__((ext_vector_type(8)));
typedef float f32x4 __attribute__((ext_vector_type(4)));

// sizes (fixed by the problem)
#define NB 8
#define BB 2
#define TT 2048
#define DD 2048
#define FF 8192
#define MM (BB * TT)          // 4096 rows
#define BTD ((size_t)BB * TT * DD)   // 8388608

__device__ __forceinline__ unsigned short f2bf(float f) {
  unsigned int u = __float_as_uint(f);
  u += 0x7FFFu + ((u >> 16) & 1u);
  return (unsigned short)(u >> 16);
}

__device__ __forceinline__ float gelu_tanh(float x) {
  float u = 0.7978845608028654f * (x + 0.044715f * x * x * x);
  float e = __expf(2.0f * u);
  float th = 1.0f - 2.0f / (e + 1.0f);   // robust tanh(u), e=inf -> 1
  return 0.5f * x * (1.0f + th);
}

template <int N>
__device__ __forceinline__ void wait_vmcnt() {
  if constexpr (N == 0) asm volatile("s_waitcnt vmcnt(0)" ::: "memory");
  else if constexpr (N == 3) asm volatile("s_waitcnt vmcnt(3)" ::: "memory");
  else if constexpr (N == 4) asm volatile("s_waitcnt vmcnt(4)" ::: "memory");
}

#define ASYNC_COPY16(gp, lp)                                                   \
  __builtin_amdgcn_global_load_lds(                                            \
      (__attribute__((address_space(1))) void*)(gp),                           \
      (__attribute__((address_space(3))) void*)(lp), 16, 0, 0)

// ---------------------------------------------------------------------------
// fp32 (R x C) -> bf16 transposed (C x R).  Vectorized: float4 in, ushort4
// out (G13: scalar fp32/bf16 accesses are ~2x slower on this path).
__global__ __launch_bounds__(256) void transpose_conv(
    const float* __restrict__ in, ushort_t* __restrict__ out, int R, int C) {
  __shared__ float tile[32][33];
  const int tx = threadIdx.x & 7;   // 8 x float4 = 32 cols
  const int ty = threadIdx.x >> 3;  // 32 rows
  const int r0 = blockIdx.y * 32, c0 = blockIdx.x * 32;
  float4 v = *(const float4*)(in + (size_t)(r0 + ty) * C + c0 + tx * 4);
  tile[ty][tx * 4 + 0] = v.x;
  tile[ty][tx * 4 + 1] = v.y;
  tile[ty][tx * 4 + 2] = v.z;
  tile[ty][tx * 4 + 3] = v.w;
  __syncthreads();
  ushort4 o;
  o.x = f2bf(tile[tx * 4 + 0][ty]);
  o.y = f2bf(tile[tx * 4 + 1][ty]);
  o.z = f2bf(tile[tx * 4 + 2][ty]);
  o.w = f2bf(tile[tx * 4 + 3][ty]);
  *(ushort4*)(out + (size_t)(c0 + ty) * R + r0 + tx * 4) = o;
}

// ---------------------------------------------------------------------------
// Fused block-attention: ONE PASS over V (V rows held in registers).
__global__ __launch_bounds__(256) void attn_fuse(
    const float* __restrict__ blocks, const float* __restrict__ partial,
    const float* __restrict__ proj_w, const float* __restrict__ norm_scale,
    float* __restrict__ h_out, ushort_t* __restrict__ h_bf) {
  const int t = threadIdx.x;
  const int bt = blockIdx.x;
  const size_t rowoff = (size_t)bt * DD;
  const int d0 = t * 4;

  float w[8];
  {
    float4 ns = *(const float4*)(norm_scale + d0);
    float4 pw = *(const float4*)(proj_w + d0);
    w[0] = ns.x * pw.x; w[1] = ns.y * pw.y; w[2] = ns.z * pw.z; w[3] = ns.w * pw.w;
    ns = *(const float4*)(norm_scale + 1024 + d0);
    pw = *(const float4*)(proj_w + 1024 + d0);
    w[4] = ns.x * pw.x; w[5] = ns.y * pw.y; w[6] = ns.z * pw.z; w[7] = ns.w * pw.w;
  }

  float vv[9][8];
  float ss[9], dt[9];
#pragma unroll
  for (int n = 0; n < 9; ++n) {
    const float* rp = (n < 8) ? (blocks + (size_t)n * BTD + rowoff)
                              : (partial + rowoff);
    float4 v0 = *(const float4*)(rp + d0);
    float4 v1 = *(const float4*)(rp + 1024 + d0);
    vv[n][0] = v0.x; vv[n][1] = v0.y; vv[n][2] = v0.z; vv[n][3] = v0.w;
    vv[n][4] = v1.x; vv[n][5] = v1.y; vv[n][6] = v1.z; vv[n][7] = v1.w;
    float a = 0.f, c = 0.f;
#pragma unroll
    for (int j = 0; j < 8; ++j) {
      a += vv[n][j] * vv[n][j];
      c += vv[n][j] * w[j];
    }
    ss[n] = a; dt[n] = c;
  }

  __shared__ float red[2][9][4];
  const int lane = t & 63, wv = t >> 6;
#pragma unroll
  for (int n = 0; n < 9; ++n) {
    float a = ss[n], c = dt[n];
#pragma unroll
    for (int off = 32; off > 0; off >>= 1) {
      a += __shfl_down(a, off, 64);
      c += __shfl_down(c, off, 64);
    }
    if (lane == 0) { red[0][n][wv] = a; red[1][n][wv] = c; }
  }
  __syncthreads();
  __shared__ float logit_s[9];
  if (t < 9) {
    float a = red[0][t][0] + red[0][t][1] + red[0][t][2] + red[0][t][3];
    float c = red[1][t][0] + red[1][t][1] + red[1][t][2] + red[1][t][3];
    logit_s[t] = c * rsqrtf(a * (1.0f / (float)DD) + 1e-8f);
  }
  __syncthreads();

  float lg[9], mx = -1e30f;
#pragma unroll
  for (int n = 0; n < 9; ++n) { lg[n] = logit_s[n]; mx = fmaxf(mx, lg[n]); }
  float den = 0.0f;
#pragma unroll
  for (int n = 0; n < 9; ++n) { lg[n] = __expf(lg[n] - mx); den += lg[n]; }
  const float inv = 1.0f / den;

  float h[8] = {0, 0, 0, 0, 0, 0, 0, 0};
#pragma unroll
  for (int n = 0; n < 9; ++n) {
    const float a = lg[n] * inv;
#pragma unroll
    for (int j = 0; j < 8; ++j) h[j] += a * vv[n][j];
  }

  float4 o0 = {h[0], h[1], h[2], h[3]}, o1 = {h[4], h[5], h[6], h[7]};
  *(float4*)(h_out + rowoff + d0) = o0;
  *(float4*)(h_out + rowoff + 1024 + d0) = o1;
  uint2 p0, p1;
  p0.x = (unsigned)f2bf(h[0]) | ((unsigned)f2bf(h[1]) << 16);
  p0.y = (unsigned)f2bf(h[2]) | ((unsigned)f2bf(h[3]) << 16);
  p1.x = (unsigned)f2bf(h[4]) | ((unsigned)f2bf(h[5]) << 16);
  p1.y = (unsigned)f2bf(h[6]) | ((unsigned)f2bf(h[7]) << 16);
  *(uint2*)(h_bf + rowoff + d0) = p0;
  *(uint2*)(h_bf + rowoff + 1024 + d0) = p1;
}

// ---------------------------------------------------------------------------
// Quad-ring bf16 GEMM with FULL fragment look-ahead at 2 waves/SIMD.
// BM=256, BK=32 sub-tiles, ring of 4 LDS buffers, one barrier per sub-tile.
// 8 waves (WM x WN), 512 threads, wave tile (256/WM) x (BN/WN).
// The R2-R10 plateau (MfmaUtil 33-39% over ten schedules) was the convoy:
// MFMA data-depended on SAME-interval ds_reads (barrier -> read -> lgkm ->
// MFMA serializes LDS and MFMA pipes CU-wide; measured interval = LDS+MFMA).
// Fix: BOTH operand fragment sets for sub-tile t+1 are ds_read during
// interval t, while MFMA(t) consumes registers loaded during t-1. The
// compiler emits a counted lgkm wait (12 outstanding) -> MFMA starts at
// barrier-exit; the new reads + stage-loads drain UNDER the MFMA stream.
// Register budget at (512,2) [the R9 occupancy lesson: >=2 waves/SIMD]:
//   GEMM1 wave 128x64: 2 sets x 12 b128 = 96 VGPR + acc 128 = ~248 <= 256.
//   GEMM2 wave  64x64: 2 sets x  8 b128 = 64 VGPR + acc  64  (safe).
// Interval t: stage(t+3)->buf[(t+3)&3] (last read at t-2, barrier-safe);
// READF frags(t+1) <- buf[(t+1)&3] (landed: vmcnt(LT) at end of t-1 leaves
// only stage(t+2) outstanding); MFMA(frags t); vmcnt(LT|0); s_barrier.
// LDS rowpair-packed XOR layout (0 bank conflicts, verified R7-R10);
// staged via pre-swizzled global source.  2D XCD supertile (verified R7).
// EPI=0: C = gelu(A@B) -> bf16.  EPI=1: C = A@B + addend -> fp32.
template <int BN, int WM, int WN, int SBY, int SBX, int MCX, int EPI>
__global__ __launch_bounds__(512, 2) void gemmR(
    const ushort_t* __restrict__ A, const ushort_t* __restrict__ BT,
    const int K, const int N, ushort_t* __restrict__ Cb,
    const float* __restrict__ addend, float* __restrict__ Cf) {
  constexpr int MFR = 256 / WM / 16;   // m-frags per wave
  constexpr int NFR = BN / WN / 16;    // n-frags per wave
  constexpr int AS = 16384;            // A sub-tile bytes (256 x 32 x 2B)
  constexpr int BS = BN * 64;          // B sub-tile bytes
  constexpr int RS = AS + BS;          // ring stride
  constexpr int LA = 2;                // A stage batches (8192 B each, 512 thr)
  constexpr int LBN = BS / 8192;       // B stage batches (2 | 1)
  constexpr int LT = LA + LBN;         // loads/thread/sub-tile (4 | 3)

  __shared__ __align__(16) char lds[4 * RS];

  const int t = threadIdx.x;
  const int lane = t & 63, wv = t >> 6;
  const int fr = lane & 15, kslot = lane >> 4;
  const int WRow = (wv / WN) * (256 / WM);
  const int WCol = (wv % WN) * (BN / WN);

  // 2D XCD supertile
  const int wg = blockIdx.x;
  const int xcd = wg & 7, local = wg >> 3;
  const int by = (xcd / MCX) * SBY + local / SBX;
  const int bx = (xcd % MCX) * SBX + local % SBX;
  const int row0 = by * 256, col0 = bx * BN;

  // staging sources: thread covers LDS bytes o = j*8192 + t*16 (linear dest);
  // global element = inverse of the rowpair+XOR layout.
  const ushort_t* ga[LA];
  const ushort_t* gb[LBN];
#pragma unroll
  for (int j = 0; j < LA; ++j) {
    const int o = j * 8192 + t * 16;
    const int rp = o >> 7;
    const int iX = (o & 127) ^ ((rp & 7) << 4);
    ga[j] = A + (size_t)(row0 + rp * 2 + (iX >> 6)) * K + ((iX & 63) >> 1);
  }
#pragma unroll
  for (int j = 0; j < LBN; ++j) {
    const int o = j * 8192 + t * 16;
    const int rp = o >> 7;
    const int iX = (o & 127) ^ ((rp & 7) << 4);
    gb[j] = BT + (size_t)(col0 + rp * 2 + (iX >> 6)) * K + ((iX & 63) >> 1);
  }

#define STAGE(QQ, KT)                                                          \
  {                                                                            \
    _Pragma("unroll") for (int j = 0; j < LA; ++j)                             \
      ASYNC_COPY16(ga[j] + (size_t)(KT) * 32,                                  \
                   lds + (QQ)*RS + j * 8192 + t * 16);                         \
    _Pragma("unroll") for (int j = 0; j < LBN; ++j)                            \
      ASYNC_COPY16(gb[j] + (size_t)(KT) * 32,                                  \
                   lds + (QQ)*RS + AS + j * 8192 + t * 16);                    \
  }

  // fragment read offsets: row r = W{Row,Col}+m*16+fr, k = kslot*8..+8:
  // byte = (r>>1)*128 + ((((r&1)<<6)|(kslot<<4)) ^ (((r>>1)&7)<<4));
  // rp&7 is m-independent (m*16 rows = 8 rowpairs).
  const int arp0 = (WRow + fr) >> 1;
  const int aoff =
      arp0 * 128 + (((((fr & 1) << 6) | (kslot << 4))) ^ ((arp0 & 7) << 4));
  const int brp0 = (WCol + fr) >> 1;
  const int boff = AS + brp0 * 128 +
                   (((((fr & 1) << 6) | (kslot << 4))) ^ ((brp0 & 7) << 4));

  // two full fragment sets: set(t) consumed while set(t+1) is read
  bf16x8 a0[MFR], b0[NFR], a1[MFR], b1[NFR];

#define READF(AX, BX, Lb)                                                      \
  {                                                                            \
    _Pragma("unroll") for (int m = 0; m < MFR; ++m)                            \
      AX[m] = *(const bf16x8*)((Lb) + aoff + m * 1024);                        \
    _Pragma("unroll") for (int n = 0; n < NFR; ++n)                            \
      BX[n] = *(const bf16x8*)((Lb) + boff + n * 1024);                        \
  }

  f32x4 acc[MFR][NFR];
#pragma unroll
  for (int m = 0; m < MFR; ++m)
#pragma unroll
    for (int n = 0; n < NFR; ++n) {
      f32x4 z = {0.f, 0.f, 0.f, 0.f};
      acc[m][n] = z;
    }

#define MFMA_(a, b, c) __builtin_amdgcn_mfma_f32_16x16x32_bf16(a, b, c, 0, 0, 0)

  // Interval: stage(t+3); READF frags(t+1) from buf(t+1); MFMA frags(t)
  // (registers only - no same-interval lgkm dependence); counted vmcnt;
  // barrier.
#define INTERVAL(QQ, KT, AC, BC, AN, BNX)                                      \
  {                                                                            \
    if ((KT) + 3 < NT) STAGE(((QQ) + 3) & 3, (KT) + 3);                        \
    if ((KT) + 1 < NT) {                                                       \
      const char* Ln = lds + (((QQ) + 1) & 3) * RS;                            \
      READF(AN, BNX, Ln);                                                      \
    }                                                                          \
    __builtin_amdgcn_s_setprio(1);                                             \
    _Pragma("unroll") for (int m = 0; m < MFR; ++m)                            \
      _Pragma("unroll") for (int n = 0; n < NFR; ++n)                          \
        acc[m][n] = MFMA_(AC[m], BC[n], acc[m][n]);                            \
    __builtin_amdgcn_s_setprio(0);                                             \
    if ((KT) + 3 < NT) wait_vmcnt<LT>(); else wait_vmcnt<0>();                 \
    __builtin_amdgcn_s_barrier();                                              \
  }

  const int NT = K >> 5;  // sub-tiles of K=32 (64 or 256; multiple of 4)

  // prologue: stage 0,1,2; wait 0,1 landed (buf2 in flight); read frags(0).
  STAGE(0, 0);
  STAGE(1, 1);
  STAGE(2, 2);
  wait_vmcnt<LT>();
  __builtin_amdgcn_s_barrier();
  READF(a0, b0, (const char*)lds);

  for (int t0 = 0; t0 < NT; t0 += 4) {
    INTERVAL(0, t0 + 0, a0, b0, a1, b1);
    INTERVAL(1, t0 + 1, a1, b1, a0, b0);
    INTERVAL(2, t0 + 2, a0, b0, a1, b1);
    INTERVAL(3, t0 + 3, a1, b1, a0, b0);
  }

  const int r4 = kslot * 4;
#pragma unroll
  for (int m = 0; m < MFR; ++m) {
    const int grow = row0 + WRow + m * 16 + r4;
#pragma unroll
    for (int n = 0; n < NFR; ++n) {
      const int gcol = col0 + WCol + n * 16 + fr;
#pragma unroll
      for (int r = 0; r < 4; ++r) {
        const float v = acc[m][n][r];
        const size_t idx = (size_t)(grow + r) * N + gcol;
        if (EPI == 0) {
          Cb[idx] = f2bf(gelu_tanh(v));
        } else {
          Cf[idx] = v + addend[idx];
        }
      }
    }
  }
#undef INTERVAL
#undef MFMA_
#undef READF
#undef STAGE
}

// ---------------------------------------------------------------------------
extern "C" void kernel_launch(void* const* d_in, const int* in_sizes, int n_in,
                              void* d_out, int out_size, void* d_ws,
                              size_t ws_size, hipStream_t stream) {
  const float* blocks = (const float*)d_in[0];
  const float* partial = (const float*)d_in[1];
  const float* proj_w = (const float*)d_in[2];
  const float* norm_scale = (const float*)d_in[3];
  const float* w1 = (const float*)d_in[4];
  const float* w2 = (const float*)d_in[5];

  float* out = (float*)d_out;
  float* h_out = out;                 // [B,T,D] fp32
  float* new_partial = out + BTD;     // [B,T,D] fp32

  char* ws = (char*)d_ws;
  ushort_t* h_bf = (ushort_t*)ws;                                        // 16 MB
  ushort_t* w1T = (ushort_t*)(ws + (size_t)16777216);                    // 32 MB (F x D)
  ushort_t* w2T = (ushort_t*)(ws + (size_t)16777216 + 33554432);         // 32 MB (D x F)
  ushort_t* act = (ushort_t*)(ws + (size_t)16777216 + 2 * 33554432ull);  // 64 MB (M x F)

  // weight convert + transpose to (N x K) bf16
  transpose_conv<<<dim3(FF / 32, DD / 32), 256, 0, stream>>>(w1, w1T, DD, FF);
  transpose_conv<<<dim3(DD / 32, FF / 32), 256, 0, stream>>>(w2, w2T, FF, DD);

  // fused attention -> h (fp32 out) + h (bf16 for GEMM)
  attn_fuse<<<MM, 256, 0, stream>>>(blocks, partial, proj_w, norm_scale, h_out,
                                    h_bf);

  // FFN: act = gelu(h @ W1) ; new_partial = act @ W2 + partial
  // GEMM1: 256x256 tile, 8 waves 2Mx4N (wave 128x64), grid 16x32=512,
  //        XCD supertile 8x8 (macro 2x4).
  gemmR<256, 2, 4, 8, 8, 4, 0><<<512, 512, 0, stream>>>(
      h_bf, w1T, DD, FF, act, nullptr, nullptr);
  // GEMM2: 256x128 tile, 8 waves 4Mx2N (wave 64x64), grid 16x16=256,
  //        XCD supertile 4x8 (macro 4x2).
  gemmR<128, 4, 2, 4, 8, 2, 1><<<256, 512, 0, stream>>>(
      act, w2T, FF, DD, nullptr, partial, new_partial);
}